// Round 6
// baseline (90.202 us; speedup 1.0000x reference)
//
#include <hip/hip_runtime.h>

// loss = || F^T F - S^T S ||_F^2 / 2^38
// F = input.reshape(64, 8192).T, S = target.reshape(64, 8192).T
// Exact rewrite of sum((FF^T+c)^d + (SS^T+c)^d - 2(FS^T+c)^d) for c=0, d=2.
//
// Single fused dispatch: phase 1 (per-block 64x64 diff-gram over a 32-k
// slice, wave-tree to one partial), manual grid barrier in d_ws, phase 2
// (each block squares+sums 16 gram entries, atomicAdd to out).

#define CH    64
#define KTOT  8192
#define G1    256            // blocks; == CU count -> all co-resident
#define KPB   32             // k per block
#define KPW   8              // k per wave (4 waves)

// 1 / (8192 * 8192 * 64 * 64) = 2^-38
#define NORMF 3.637978807091713e-12f

// Partials: G1 * 4096 floats = 4 MiB; barrier counters live after them.
#define PART_FLOATS (G1 * 4096)

// Swizzled column for cross-wave reduce buffer (breaks the 8-way conflict
// from the 256 B row stride; tb^row is a Latin square over {0,8,..,56}).
#define RCOL(row, tb) ((tb) ^ ((row) & 56))

__global__ __launch_bounds__(256) void fused_loss(
    const float* __restrict__ in, const float* __restrict__ tg,
    float* __restrict__ ws, float* __restrict__ out)
{
    __shared__ __attribute__((aligned(16))) float ts_in[KPB][CH];   // 8 KiB
    __shared__ __attribute__((aligned(16))) float ts_tg[KPB][CH];   // 8 KiB
    __shared__ __attribute__((aligned(16))) float red[2][CH][CH];   // 32 KiB

    const int t  = threadIdx.x;
    const int b  = blockIdx.x;
    const int k0 = b * KPB;

    // Zero the scalar accumulator before the barrier; the barrier's
    // release/acquire chain orders it before any phase-2 atomicAdd.
    if (b == 0 && t == 0) out[0] = 0.f;

    // ---- phase 1a: stage global -> LDS, transpose-on-write ----
    {
        const int lk = (t & 7) << 2;             // 0,4,...,28
#pragma unroll
        for (int r = 0; r < 2; ++r) {
            const int lch = (t >> 3) + 32 * r;   // 0..63
            const float4 vi = *(const float4*)(in + lch * KTOT + k0 + lk);
            const float4 vt = *(const float4*)(tg + lch * KTOT + k0 + lk);
            ts_in[lk + 0][lch] = vi.x; ts_in[lk + 1][lch] = vi.y;
            ts_in[lk + 2][lch] = vi.z; ts_in[lk + 3][lch] = vi.w;
            ts_tg[lk + 0][lch] = vt.x; ts_tg[lk + 1][lch] = vt.y;
            ts_tg[lk + 2][lch] = vt.z; ts_tg[lk + 3][lch] = vt.w;
        }
    }
    __syncthreads();

    // ---- phase 1b: wave w covers kk in [w*8, w*8+8); 8x8 tile per lane ----
    const int w    = t >> 6;             // 0..3
    const int lane = t & 63;
    const int ta   = (lane >> 3) << 3;   // 0,8,...,56
    const int tb   = (lane & 7) << 3;    // 0,8,...,56

    float acc[8][8];
#pragma unroll
    for (int i = 0; i < 8; ++i)
#pragma unroll
        for (int j = 0; j < 8; ++j) acc[i][j] = 0.f;

#pragma unroll
    for (int kk = w * KPW; kk < w * KPW + KPW; ++kk) {
        const float4 x0 = *(const float4*)&ts_in[kk][ta];
        const float4 x1 = *(const float4*)&ts_in[kk][ta + 4];
        const float4 y0 = *(const float4*)&ts_in[kk][tb];
        const float4 y1 = *(const float4*)&ts_in[kk][tb + 4];
        const float4 u0 = *(const float4*)&ts_tg[kk][ta];
        const float4 u1 = *(const float4*)&ts_tg[kk][ta + 4];
        const float4 v0 = *(const float4*)&ts_tg[kk][tb];
        const float4 v1 = *(const float4*)&ts_tg[kk][tb + 4];
        const float A[8] = {x0.x, x0.y, x0.z, x0.w, x1.x, x1.y, x1.z, x1.w};
        const float B[8] = {y0.x, y0.y, y0.z, y0.w, y1.x, y1.y, y1.z, y1.w};
        const float C[8] = {u0.x, u0.y, u0.z, u0.w, u1.x, u1.y, u1.z, u1.w};
        const float D[8] = {v0.x, v0.y, v0.z, v0.w, v1.x, v1.y, v1.z, v1.w};
#pragma unroll
        for (int i = 0; i < 8; ++i)
#pragma unroll
            for (int j = 0; j < 8; ++j) {
                acc[i][j] = fmaf(A[i], B[j], acc[i][j]);
                acc[i][j] = fmaf(-C[i], D[j], acc[i][j]);
            }
    }

    // ---- phase 1c: wave tree 4 -> 2 -> 1, then write one partial ----
    if (w >= 2) {
#pragma unroll
        for (int i = 0; i < 8; ++i) {
            const int row = ta + i;
            const int cc  = RCOL(row, tb);
            float4 a, bb;
            a.x  = acc[i][0]; a.y  = acc[i][1]; a.z  = acc[i][2]; a.w  = acc[i][3];
            bb.x = acc[i][4]; bb.y = acc[i][5]; bb.z = acc[i][6]; bb.w = acc[i][7];
            *(float4*)&red[w - 2][row][cc]     = a;
            *(float4*)&red[w - 2][row][cc + 4] = bb;
        }
    }
    __syncthreads();
    if (w < 2) {
#pragma unroll
        for (int i = 0; i < 8; ++i) {
            const int row = ta + i;
            const int cc  = RCOL(row, tb);
            const float4 r0 = *(const float4*)&red[w][row][cc];
            const float4 r1 = *(const float4*)&red[w][row][cc + 4];
            acc[i][0] += r0.x; acc[i][1] += r0.y; acc[i][2] += r0.z; acc[i][3] += r0.w;
            acc[i][4] += r1.x; acc[i][5] += r1.y; acc[i][6] += r1.z; acc[i][7] += r1.w;
        }
    }
    __syncthreads();                       // red[0] readers done before reuse
    if (w == 1) {
#pragma unroll
        for (int i = 0; i < 8; ++i) {
            const int row = ta + i;
            const int cc  = RCOL(row, tb);
            float4 a, bb;
            a.x  = acc[i][0]; a.y  = acc[i][1]; a.z  = acc[i][2]; a.w  = acc[i][3];
            bb.x = acc[i][4]; bb.y = acc[i][5]; bb.z = acc[i][6]; bb.w = acc[i][7];
            *(float4*)&red[0][row][cc]     = a;
            *(float4*)&red[0][row][cc + 4] = bb;
        }
    }
    __syncthreads();
    if (w == 0) {
        float* p = ws + b * 4096;
#pragma unroll
        for (int i = 0; i < 8; ++i) {
            const int row = ta + i;
            const int cc  = RCOL(row, tb);
            const float4 r0 = *(const float4*)&red[0][row][cc];
            const float4 r1 = *(const float4*)&red[0][row][cc + 4];
            float4 a, bb;
            a.x  = acc[i][0] + r0.x; a.y  = acc[i][1] + r0.y;
            a.z  = acc[i][2] + r0.z; a.w  = acc[i][3] + r0.w;
            bb.x = acc[i][4] + r1.x; bb.y = acc[i][5] + r1.y;
            bb.z = acc[i][6] + r1.z; bb.w = acc[i][7] + r1.w;
            *(float4*)(p + row * 64 + tb)     = a;
            *(float4*)(p + row * 64 + tb + 4) = bb;
        }
    }
    __syncthreads();   // all partial stores issued before t0's release-RMW

    // ---- grid barrier (self-cleaning, poison-value independent) ----
    // Invariant at kernel entry: A == B (uniform poison, or restored by the
    // previous call's B-bumps). Snapshot S=B is taken before this block's
    // A-increment; B cannot advance until all 256 A-increments have landed,
    // so the spin target S+G1 is exact and A is monotone -> no lost wakeup.
    {
        unsigned* ctr = (unsigned*)(ws + PART_FLOATS);
        unsigned* A   = ctr;
        unsigned* B   = ctr + 32;        // 128 B apart, same poison value
        if (t == 0) {
            unsigned S = __hip_atomic_load(B, __ATOMIC_RELAXED,
                                           __HIP_MEMORY_SCOPE_AGENT);
            __hip_atomic_fetch_add(A, 1u, __ATOMIC_RELEASE,
                                   __HIP_MEMORY_SCOPE_AGENT);
            while (__hip_atomic_load(A, __ATOMIC_ACQUIRE,
                                     __HIP_MEMORY_SCOPE_AGENT) - S < (unsigned)G1)
                __builtin_amdgcn_s_sleep(2);
            __threadfence();
        }
        __syncthreads();
    }

    // ---- phase 2: block b owns gram entries [b*16, b*16+16) ----
    {
        const int el = t & 15;                 // entry within block
        const int sl = t >> 4;                 // slice 0..15
        const int e  = (b << 4) + el;
        float s = 0.f;
#pragma unroll
        for (int p = sl * 16; p < sl * 16 + 16; ++p)   // 16 independent loads
            s += ws[p * 4096 + e];
        float* r2 = &red[0][0][0];
        r2[sl * 16 + el] = s;
    }
    __syncthreads();
    if (t < 64) {
        const float* r2 = &red[0][0][0];
        float sq = 0.f;
        if (t < 16) {
            float tot = 0.f;
#pragma unroll
            for (int i = 0; i < 16; ++i) tot += r2[i * 16 + t];
            sq = tot * tot;
        }
#pragma unroll
        for (int off = 8; off > 0; off >>= 1)
            sq += __shfl_down(sq, off);
        if (t == 0) atomicAdd(out, sq * NORMF);
    }

    // ---- self-clean: restore A == B for the next (possibly unpoisoned) call
    if (t == 0) {
        unsigned* B = (unsigned*)(ws + PART_FLOATS) + 32;
        __hip_atomic_fetch_add(B, 1u, __ATOMIC_RELEASE,
                               __HIP_MEMORY_SCOPE_AGENT);
    }
}

extern "C" void kernel_launch(void* const* d_in, const int* in_sizes, int n_in,
                              void* d_out, int out_size, void* d_ws, size_t ws_size,
                              hipStream_t stream)
{
    const float* in = (const float*)d_in[0];
    const float* tg = (const float*)d_in[1];
    float* out = (float*)d_out;
    float* ws  = (float*)d_ws;   // 4 MiB partials + barrier counters

    fused_loss<<<G1, 256, 0, stream>>>(in, tg, ws, out);
}

// Round 7
// 62.388 us; speedup vs baseline: 1.4458x; 1.4458x over previous
//
#include <hip/hip_runtime.h>

// loss = || F^T F - S^T S ||_F^2 / 2^38
// F = input.reshape(64, 8192).T, S = target.reshape(64, 8192).T
// Exact rewrite of sum((FF^T+c)^d + (SS^T+c)^d - 2(FS^T+c)^d) for c=0, d=2:
//   sum_ij (f_i.f_j)^2 = ||F^T F||_F^2  etc., cross term = <F^T F, S^T S>.
//
// Structure note (measured): 2 dispatches is optimal. A fused single-dispatch
// with an in-ws grid barrier cost +27 us (R6) vs the ~3.7 us a dispatch
// boundary costs (R2->R3). Kernel boundaries are the cheap grid barrier.

#define CH    64
#define KTOT  8192
#define G1    256            // gram blocks
#define KPB   (KTOT / G1)    // 32 k per block
#define KPG   (KPB / 2)      // 16 k per 256-thread group

// 1 / (8192 * 8192 * 64 * 64) = 2^-38
#define NORMF 3.637978807091713e-12f

__global__ __launch_bounds__(512, 4) void gram_partial(
    const float* __restrict__ in, const float* __restrict__ tg,
    float* __restrict__ ws, float* __restrict__ out)
{
    // Transposed tiles [k][ch]: fragment reads contiguous in ch.
    __shared__ __attribute__((aligned(16))) float ts_in[KPB][CH];   // 8 KiB
    __shared__ __attribute__((aligned(16))) float ts_tg[KPB][CH];   // 8 KiB
    __shared__ __attribute__((aligned(16))) float red[4096];        // 16 KiB

    const int t  = threadIdx.x;            // 0..511
    const int k0 = blockIdx.x * KPB;

    // zero the output accumulator (ordered before reduce_square's atomics
    // by the kernel boundary)
    if (blockIdx.x == 0 && t == 0) out[0] = 0.f;

    // --- stage: thread t loads one float4 per matrix ---
    {
        const int lch = t >> 3;            // 0..63
        const int lko = (t & 7) << 2;      // 0,4,..,28
        const float4 vi = *(const float4*)(in + lch * KTOT + k0 + lko);
        const float4 vt = *(const float4*)(tg + lch * KTOT + k0 + lko);
        ts_in[lko + 0][lch] = vi.x; ts_in[lko + 1][lch] = vi.y;
        ts_in[lko + 2][lch] = vi.z; ts_in[lko + 3][lch] = vi.w;
        ts_tg[lko + 0][lch] = vt.x; ts_tg[lko + 1][lch] = vt.y;
        ts_tg[lko + 2][lch] = vt.z; ts_tg[lko + 3][lch] = vt.w;
    }
    __syncthreads();

    // --- compute: group g handles kk in [g*KPG, (g+1)*KPG) ---
    const int g   = t >> 8;                // 0..1
    const int tid = t & 255;               // 0..255
    const int ty  = tid >> 4;              // 0..15
    const int tx  = tid & 15;              // 0..15
    const int a0  = ty << 2;
    const int b0  = tx << 2;

    float acc[4][4];
#pragma unroll
    for (int i = 0; i < 4; ++i)
#pragma unroll
        for (int j = 0; j < 4; ++j) acc[i][j] = 0.f;

#pragma unroll
    for (int kk = g * KPG; kk < g * KPG + KPG; ++kk) {
        const float4 av = *(const float4*)&ts_in[kk][a0];
        const float4 bv = *(const float4*)&ts_in[kk][b0];
        const float4 cv = *(const float4*)&ts_tg[kk][a0];
        const float4 dv = *(const float4*)&ts_tg[kk][b0];
        const float aa[4] = {av.x, av.y, av.z, av.w};
        const float bb[4] = {bv.x, bv.y, bv.z, bv.w};
        const float cc[4] = {cv.x, cv.y, cv.z, cv.w};
        const float dd[4] = {dv.x, dv.y, dv.z, dv.w};
#pragma unroll
        for (int i = 0; i < 4; ++i)
#pragma unroll
            for (int j = 0; j < 4; ++j) {
                acc[i][j] = fmaf(aa[i], bb[j], acc[i][j]);
                acc[i][j] = fmaf(-cc[i], dd[j], acc[i][j]);
            }
    }

    // --- block reduce (group 1 -> LDS, group 0 adds) and store ---
    if (g == 1) {
#pragma unroll
        for (int i = 0; i < 4; ++i) {
            float4 v;
            v.x = acc[i][0]; v.y = acc[i][1]; v.z = acc[i][2]; v.w = acc[i][3];
            *(float4*)&red[tid * 16 + i * 4] = v;
        }
    }
    __syncthreads();
    if (g == 0) {
        float* p = ws + blockIdx.x * 4096;
#pragma unroll
        for (int i = 0; i < 4; ++i) {
            const float4 r = *(const float4*)&red[tid * 16 + i * 4];
            float4 v;
            v.x = acc[i][0] + r.x; v.y = acc[i][1] + r.y;
            v.z = acc[i][2] + r.z; v.w = acc[i][3] + r.w;
            *(float4*)(p + (a0 + i) * 64 + b0) = v;
        }
    }
}

__global__ __launch_bounds__(256) void reduce_square(
    const float* __restrict__ ws, float* __restrict__ out)
{
    // 64 blocks x 64 entries; 4 slices of 64 partials per entry
    __shared__ float red2[4][64];
    const int t  = threadIdx.x;
    const int el = t & 63;                     // entry within block
    const int sl = t >> 6;                     // 0..3
    const int e  = (blockIdx.x << 6) + el;     // gram entry 0..4095

    float s = 0.f;
    const int p0 = sl * (G1 / 4);
#pragma unroll 16
    for (int p = p0; p < p0 + (G1 / 4); ++p)
        s += ws[p * 4096 + e];
    red2[sl][el] = s;
    __syncthreads();

    if (t < 64) {                              // wave 0
        float tot = red2[0][t] + red2[1][t] + red2[2][t] + red2[3][t];
        float sq  = tot * tot;
#pragma unroll
        for (int off = 32; off > 0; off >>= 1)
            sq += __shfl_down(sq, off);
        if (t == 0) atomicAdd(out, sq * NORMF);
    }
}

extern "C" void kernel_launch(void* const* d_in, const int* in_sizes, int n_in,
                              void* d_out, int out_size, void* d_ws, size_t ws_size,
                              hipStream_t stream)
{
    const float* in = (const float*)d_in[0];
    const float* tg = (const float*)d_in[1];
    float* out = (float*)d_out;
    float* ws  = (float*)d_ws;   // uses G1*4096*4 = 4 MiB

    gram_partial<<<G1, 512, 0, stream>>>(in, tg, ws, out);
    reduce_square<<<64, 256, 0, stream>>>(ws, out);
}